// Round 1
// baseline (990.662 us; speedup 1.0000x reference)
//
#include <hip/hip_runtime.h>
#include <hip/hip_bf16.h>
#include <stdint.h>

#define S 2048
#define D 2048
#define H 16
#define HD 128

typedef __bf16 bf16x8 __attribute__((ext_vector_type(8)));
typedef __bf16 bf16x4 __attribute__((ext_vector_type(4)));
typedef float f32x4 __attribute__((ext_vector_type(4)));

// ---------------- f32 -> bf16 convert (exact-grid, 4 elems/thread) ----------
__global__ void f32_to_bf16_kn(const float* __restrict__ in, __bf16* __restrict__ out, int n4) {
    int i = blockIdx.x * 256 + threadIdx.x;
    if (i < n4) {
        float4 v = reinterpret_cast<const float4*>(in)[i];
        bf16x4 o = { (__bf16)v.x, (__bf16)v.y, (__bf16)v.z, (__bf16)v.w };
        reinterpret_cast<bf16x4*>(out)[i] = o;
    }
}

// ---------------- RoPE (in-place, pairs within each head) -------------------
__global__ void rope_kn(__bf16* __restrict__ t, const float* __restrict__ cs,
                        const float* __restrict__ sn) {
    int idx = blockIdx.x * 256 + threadIdx.x;      // < S*D/2
    int s = idx >> 10;                             // D/2 = 1024
    int p = idx & 1023;
    int i = p & 63;                                // pair index within head (hd/2=64)
    size_t a = (size_t)s * D + 2 * p;
    float r  = (float)t[a];
    float im = (float)t[a + 1];
    float c  = cs[s * 64 + i];
    float sv = sn[s * 64 + i];
    t[a]     = (__bf16)(r * c - im * sv);
    t[a + 1] = (__bf16)(r * sv + im * c);
}

// ---------------- bf16 transpose (S,D) -> (D,S) -----------------------------
__global__ void transpose_kn(const __bf16* __restrict__ in, __bf16* __restrict__ out) {
    __shared__ __bf16 tile[32][33];
    int tx = threadIdx.x, ty = threadIdx.y;
    int x  = blockIdx.x * 32 + tx;
    int y0 = blockIdx.y * 32;
#pragma unroll
    for (int j = 0; j < 32; j += 8)
        tile[ty + j][tx] = in[(size_t)(y0 + ty + j) * D + x];
    __syncthreads();
    int x2 = y0 + tx;                 // s
    int y2 = blockIdx.x * 32 + ty;    // d
#pragma unroll
    for (int j = 0; j < 32; j += 8)
        out[(size_t)(y2 + j) * S + x2] = tile[tx][ty + j];
}

// ---------------- GEMM: C[M,N] = alpha*(A[M,K] @ B[N,K]^T + bias[N]) --------
// B^T layout (K contiguous in both A and B) — matches x@W^T einsum.
template <int OUT_BF16>
__global__ __launch_bounds__(256) void gemm_bt(const __bf16* __restrict__ A,
                                               const __bf16* __restrict__ B,
                                               const float* __restrict__ bias,
                                               void* __restrict__ Cv, float alpha,
                                               int M, int N, int K) {
    __shared__ __bf16 As[128][40];   // +8 pad: stride 80B -> 2-way banks (free)
    __shared__ __bf16 Bs[128][40];
    const int tid = threadIdx.x;
    const int wave = tid >> 6, lane = tid & 63;
    const int lr = lane & 15, lq = lane >> 4;
    const int wm = (wave >> 1) * 64, wn = (wave & 1) * 64;
    const int row0 = blockIdx.y * 128, col0 = blockIdx.x * 128;

    f32x4 acc[4][4] = {};

    for (int k0 = 0; k0 < K; k0 += 32) {
#pragma unroll
        for (int i = 0; i < 2; i++) {
            int idx = tid + i * 256;          // 512 chunks of 8 bf16
            int r = idx >> 2, c = (idx & 3) * 8;
            *reinterpret_cast<uint4*>(&As[r][c]) =
                *reinterpret_cast<const uint4*>(&A[(size_t)(row0 + r) * K + k0 + c]);
            *reinterpret_cast<uint4*>(&Bs[r][c]) =
                *reinterpret_cast<const uint4*>(&B[(size_t)(col0 + r) * K + k0 + c]);
        }
        __syncthreads();
        bf16x8 af[4], bfr[4];
#pragma unroll
        for (int mt = 0; mt < 4; mt++)
            af[mt] = *reinterpret_cast<const bf16x8*>(&As[wm + mt * 16 + lr][lq * 8]);
#pragma unroll
        for (int nt = 0; nt < 4; nt++)
            bfr[nt] = *reinterpret_cast<const bf16x8*>(&Bs[wn + nt * 16 + lr][lq * 8]);
#pragma unroll
        for (int mt = 0; mt < 4; mt++)
#pragma unroll
            for (int nt = 0; nt < 4; nt++)
                acc[mt][nt] = __builtin_amdgcn_mfma_f32_16x16x32_bf16(af[mt], bfr[nt],
                                                                      acc[mt][nt], 0, 0, 0);
        __syncthreads();
    }
#pragma unroll
    for (int mt = 0; mt < 4; mt++) {
#pragma unroll
        for (int nt = 0; nt < 4; nt++) {
            int col = col0 + wn + nt * 16 + lr;
            float bv = bias[col];
#pragma unroll
            for (int r = 0; r < 4; r++) {
                int row = row0 + wm + mt * 16 + lq * 4 + r;  // C layout: row=(lane>>4)*4+reg
                float v = alpha * (acc[mt][nt][r] + bv);
                if (OUT_BF16)
                    ((__bf16*)Cv)[(size_t)row * N + col] = (__bf16)v;
                else
                    ((float*)Cv)[(size_t)row * N + col] = v;
            }
        }
    }
}

// ---------------- Pass A: rdenom[h][s] = 1/clip(sum_t |q·k|, 1, 5e4) --------
__global__ __launch_bounds__(256) void denom_kn(const __bf16* __restrict__ q,
                                                const __bf16* __restrict__ k,
                                                float* __restrict__ rdenom) {
    __shared__ __bf16 Ks[64][136];
    const int h = blockIdx.y, qt = blockIdx.x;
    const int tid = threadIdx.x, wave = tid >> 6, lane = tid & 63;
    const int lr = lane & 15, lq = lane >> 4;
    const int qr0 = qt * 64 + wave * 16;

    bf16x8 qf[4];
#pragma unroll
    for (int kc = 0; kc < 4; kc++)
        qf[kc] = *reinterpret_cast<const bf16x8*>(
            &q[(size_t)(qr0 + lr) * D + h * HD + kc * 32 + lq * 8]);

    float absacc[4] = {0.f, 0.f, 0.f, 0.f};

    for (int t0 = 0; t0 < S; t0 += 64) {
#pragma unroll
        for (int i = 0; i < 4; i++) {
            int idx = tid + i * 256;
            int r = idx >> 4, c = (idx & 15) * 8;
            *reinterpret_cast<uint4*>(&Ks[r][c]) =
                *reinterpret_cast<const uint4*>(&k[(size_t)(t0 + r) * D + h * HD + c]);
        }
        __syncthreads();
#pragma unroll
        for (int ts = 0; ts < 4; ts++) {
            f32x4 c = {0.f, 0.f, 0.f, 0.f};
#pragma unroll
            for (int kc = 0; kc < 4; kc++) {
                bf16x8 kf = *reinterpret_cast<const bf16x8*>(&Ks[ts * 16 + lr][kc * 32 + lq * 8]);
                c = __builtin_amdgcn_mfma_f32_16x16x32_bf16(qf[kc], kf, c, 0, 0, 0);
            }
#pragma unroll
            for (int r2 = 0; r2 < 4; r2++) absacc[r2] += fabsf(c[r2]);
        }
        __syncthreads();
    }
#pragma unroll
    for (int r2 = 0; r2 < 4; r2++) {
        float v = absacc[r2];
#pragma unroll
        for (int off = 1; off < 16; off <<= 1) v += __shfl_xor(v, off, 64);
        if (lr == 0) {
            float d = fminf(fmaxf(v, 1.0f), 50000.0f);
            rdenom[h * S + qr0 + lq * 4 + r2] = 1.0f / d;
        }
    }
}

// ---------------- Pass B: O = (QK^T * rdenom + mask) @ V, then RMS*nw*g -----
__global__ __launch_bounds__(256) void attn_kn(const __bf16* __restrict__ q,
                                               const __bf16* __restrict__ k,
                                               const __bf16* __restrict__ vT,
                                               const float* __restrict__ mask,
                                               const float* __restrict__ rdenom,
                                               const __bf16* __restrict__ g,
                                               const float* __restrict__ norm_w,
                                               __bf16* __restrict__ attn) {
    __shared__ __bf16 Ks[64][136];
    __shared__ __bf16 Vs[128][72];
    __shared__ __bf16 Ps[4][16][72];   // per-wave P tile (16 q-rows x 64 t)
    const int h = blockIdx.y, qt = blockIdx.x;
    const int tid = threadIdx.x, wave = tid >> 6, lane = tid & 63;
    const int lr = lane & 15, lq = lane >> 4;
    const int qr0 = qt * 64 + wave * 16;

    bf16x8 qf[4];
#pragma unroll
    for (int kc = 0; kc < 4; kc++)
        qf[kc] = *reinterpret_cast<const bf16x8*>(
            &q[(size_t)(qr0 + lr) * D + h * HD + kc * 32 + lq * 8]);
    float rd[4];
#pragma unroll
    for (int r2 = 0; r2 < 4; r2++) rd[r2] = rdenom[h * S + qr0 + lq * 4 + r2];

    f32x4 o[8] = {};

    for (int t0 = 0; t0 < S; t0 += 64) {
#pragma unroll
        for (int i = 0; i < 4; i++) {
            int idx = tid + i * 256;
            int rk = idx >> 4, ck = (idx & 15) * 8;
            *reinterpret_cast<uint4*>(&Ks[rk][ck]) =
                *reinterpret_cast<const uint4*>(&k[(size_t)(t0 + rk) * D + h * HD + ck]);
            int rv = idx >> 3, cv = (idx & 7) * 8;
            *reinterpret_cast<uint4*>(&Vs[rv][cv]) =
                *reinterpret_cast<const uint4*>(&vT[(size_t)(h * HD + rv) * S + t0 + cv]);
        }
        __syncthreads();
#pragma unroll
        for (int ts = 0; ts < 4; ts++) {
            f32x4 c = {0.f, 0.f, 0.f, 0.f};
#pragma unroll
            for (int kc = 0; kc < 4; kc++) {
                bf16x8 kf = *reinterpret_cast<const bf16x8*>(&Ks[ts * 16 + lr][kc * 32 + lq * 8]);
                c = __builtin_amdgcn_mfma_f32_16x16x32_bf16(qf[kc], kf, c, 0, 0, 0);
            }
#pragma unroll
            for (int r2 = 0; r2 < 4; r2++) {
                float m = mask[((size_t)h * S + qr0 + lq * 4 + r2) * S + t0 + ts * 16 + lr];
                Ps[wave][lq * 4 + r2][ts * 16 + lr] = (__bf16)(c[r2] * rd[r2] + m);
            }
        }
        // P (A-layout read, per-wave private region; same-wave LDS ordering is safe)
#pragma unroll
        for (int kc2 = 0; kc2 < 2; kc2++) {
            bf16x8 pf = *reinterpret_cast<const bf16x8*>(&Ps[wave][lr][kc2 * 32 + lq * 8]);
#pragma unroll
            for (int nt = 0; nt < 8; nt++) {
                bf16x8 vf = *reinterpret_cast<const bf16x8*>(&Vs[nt * 16 + lr][kc2 * 32 + lq * 8]);
                o[nt] = __builtin_amdgcn_mfma_f32_16x16x32_bf16(pf, vf, o[nt], 0, 0, 0);
            }
        }
        __syncthreads();
    }
    // epilogue: RMS over hd=128, * norm_w[col] * g
    float ssum[4] = {0.f, 0.f, 0.f, 0.f};
#pragma unroll
    for (int nt = 0; nt < 8; nt++)
#pragma unroll
        for (int r2 = 0; r2 < 4; r2++) ssum[r2] += o[nt][r2] * o[nt][r2];
#pragma unroll
    for (int r2 = 0; r2 < 4; r2++) {
#pragma unroll
        for (int off = 1; off < 16; off <<= 1) ssum[r2] += __shfl_xor(ssum[r2], off, 64);
    }
    float rinv[4];
#pragma unroll
    for (int r2 = 0; r2 < 4; r2++) rinv[r2] = rsqrtf(ssum[r2] * (1.0f / HD) + 1e-5f);
#pragma unroll
    for (int nt = 0; nt < 8; nt++) {
        int col = nt * 16 + lr;
        float nw = norm_w[col];
#pragma unroll
        for (int r2 = 0; r2 < 4; r2++) {
            int row = qr0 + lq * 4 + r2;
            float val = o[nt][r2] * rinv[r2] * nw * (float)g[(size_t)row * D + h * HD + col];
            attn[(size_t)row * D + h * HD + col] = (__bf16)val;
        }
    }
}

extern "C" void kernel_launch(void* const* d_in, const int* in_sizes, int n_in,
                              void* d_out, int out_size, void* d_ws, size_t ws_size,
                              hipStream_t stream) {
    const float* x    = (const float*)d_in[0];
    const float* fcos = (const float*)d_in[1];
    const float* fsin = (const float*)d_in[2];
    const float* mask = (const float*)d_in[3];
    const float* Wq   = (const float*)d_in[4];
    const float* bq   = (const float*)d_in[5];
    const float* Wk   = (const float*)d_in[6];
    const float* bk   = (const float*)d_in[7];
    const float* Wv   = (const float*)d_in[8];
    const float* bv   = (const float*)d_in[9];
    const float* Wg   = (const float*)d_in[10];
    const float* bg   = (const float*)d_in[11];
    const float* Wp   = (const float*)d_in[12];
    const float* bp   = (const float*)d_in[13];
    const float* normw= (const float*)d_in[14];

    char* w = (char*)d_ws;
    auto alloc = [&](size_t b) { void* p = (void*)w; w += (b + 255) & ~(size_t)255; return p; };
    const size_t SD = (size_t)S * D;

    __bf16* xb  = (__bf16*)alloc(SD * 2);
    __bf16* wqb = (__bf16*)alloc(SD * 2);
    __bf16* wkb = (__bf16*)alloc(SD * 2);
    __bf16* wvb = (__bf16*)alloc(SD * 2);
    __bf16* wgb = (__bf16*)alloc(SD * 2);
    __bf16* wpb = (__bf16*)alloc(SD * 2);
    __bf16* qb  = (__bf16*)alloc(SD * 2);
    __bf16* kb  = (__bf16*)alloc(SD * 2);
    __bf16* vb  = (__bf16*)alloc(SD * 2);
    __bf16* gb  = (__bf16*)alloc(SD * 2);
    __bf16* vTb = (__bf16*)alloc(SD * 2);
    __bf16* atb = (__bf16*)alloc(SD * 2);
    float* rden = (float*)alloc((size_t)H * S * 4);

    const int n4 = (int)(SD / 4);
    const int cb = n4 / 256;
    f32_to_bf16_kn<<<cb, 256, 0, stream>>>(x,  xb,  n4);
    f32_to_bf16_kn<<<cb, 256, 0, stream>>>(Wq, wqb, n4);
    f32_to_bf16_kn<<<cb, 256, 0, stream>>>(Wk, wkb, n4);
    f32_to_bf16_kn<<<cb, 256, 0, stream>>>(Wv, wvb, n4);
    f32_to_bf16_kn<<<cb, 256, 0, stream>>>(Wg, wgb, n4);
    f32_to_bf16_kn<<<cb, 256, 0, stream>>>(Wp, wpb, n4);

    dim3 gg(16, 16);
    const float scaling = 0.08838834764831845f;  // 128^-0.5
    gemm_bt<1><<<gg, 256, 0, stream>>>(xb, wqb, bq, qb, 1.0f,    S, D, D);
    gemm_bt<1><<<gg, 256, 0, stream>>>(xb, wkb, bk, kb, scaling, S, D, D);
    gemm_bt<1><<<gg, 256, 0, stream>>>(xb, wvb, bv, vb, 1.0f,    S, D, D);
    gemm_bt<1><<<gg, 256, 0, stream>>>(xb, wgb, bg, gb, 1.0f,    S, D, D);

    rope_kn<<<(S * D / 2) / 256, 256, 0, stream>>>(qb, fcos, fsin);
    rope_kn<<<(S * D / 2) / 256, 256, 0, stream>>>(kb, fcos, fsin);

    transpose_kn<<<dim3(64, 64), dim3(32, 8), 0, stream>>>(vb, vTb);

    denom_kn<<<dim3(32, 16), 256, 0, stream>>>(qb, kb, rden);
    attn_kn<<<dim3(32, 16), 256, 0, stream>>>(qb, kb, vTb, mask, rden, gb, normw, atb);

    gemm_bt<0><<<gg, 256, 0, stream>>>(atb, wpb, bp, (float*)d_out, 1.0f, S, D, D);
}

// Round 2
// 757.537 us; speedup vs baseline: 1.3077x; 1.3077x over previous
//
#include <hip/hip_runtime.h>
#include <hip/hip_bf16.h>
#include <stdint.h>

#define S 2048
#define D 2048
#define H 16
#define HD 128

typedef __bf16 bf16x8 __attribute__((ext_vector_type(8)));
typedef __bf16 bf16x4 __attribute__((ext_vector_type(4)));
typedef float f32x4 __attribute__((ext_vector_type(4)));

// async global->LDS DMA, 16B per lane; LDS dest = wave-uniform base + lane*16
__device__ __forceinline__ void gload16(const void* g, void* l) {
    __builtin_amdgcn_global_load_lds(
        (const __attribute__((address_space(1))) unsigned int*)g,
        (__attribute__((address_space(3))) unsigned int*)l, 16, 0, 0);
}

// ---------------- f32 -> bf16 convert ---------------------------------------
__global__ void f32_to_bf16_kn(const float* __restrict__ in, __bf16* __restrict__ out, int n4) {
    int i = blockIdx.x * 256 + threadIdx.x;
    if (i < n4) {
        float4 v = reinterpret_cast<const float4*>(in)[i];
        bf16x4 o = { (__bf16)v.x, (__bf16)v.y, (__bf16)v.z, (__bf16)v.w };
        reinterpret_cast<bf16x4*>(out)[i] = o;
    }
}

// ---------------- RoPE (in-place) -------------------------------------------
__global__ void rope_kn(__bf16* __restrict__ t, const float* __restrict__ cs,
                        const float* __restrict__ sn) {
    int idx = blockIdx.x * 256 + threadIdx.x;      // < S*D/2
    int s = idx >> 10;
    int p = idx & 1023;
    int i = p & 63;
    size_t a = (size_t)s * D + 2 * p;
    float r  = (float)t[a];
    float im = (float)t[a + 1];
    float c  = cs[s * 64 + i];
    float sv = sn[s * 64 + i];
    t[a]     = (__bf16)(r * c - im * sv);
    t[a + 1] = (__bf16)(r * sv + im * c);
}

// ---------------- bf16 transpose (S,D) -> (D,S) -----------------------------
__global__ void transpose_kn(const __bf16* __restrict__ in, __bf16* __restrict__ out) {
    __shared__ __bf16 tile[32][33];
    int tx = threadIdx.x, ty = threadIdx.y;
    int x  = blockIdx.x * 32 + tx;
    int y0 = blockIdx.y * 32;
#pragma unroll
    for (int j = 0; j < 32; j += 8)
        tile[ty + j][tx] = in[(size_t)(y0 + ty + j) * D + x];
    __syncthreads();
    int x2 = y0 + tx;
    int y2 = blockIdx.x * 32 + ty;
#pragma unroll
    for (int j = 0; j < 32; j += 8)
        out[(size_t)(y2 + j) * S + x2] = tile[tx][ty + j];
}

// ---------------- fused multi-output GEMM (m97 structure) -------------------
// C_seg[M,2048] = alpha*(A[M,K] @ Bseg[N,K]^T + bias_seg); seg = blockIdx.x>>4
struct SegArgs {
    const __bf16* B[4];
    const float*  bias[4];
    void*         C[4];
    float         alpha[4];
};

template <int OUT_BF16>
__global__ __launch_bounds__(256) void gemm4_kn(const __bf16* __restrict__ A,
                                                SegArgs segs, int K) {
    __shared__ __bf16 As[128][32];   // unpadded: required by global_load_lds
    __shared__ __bf16 Bs[128][32];
    const int tid = threadIdx.x;
    const int wave = tid >> 6, lane = tid & 63;
    const int lr = lane & 15, lq = lane >> 4;
    const int wm = (wave >> 1) * 64, wn = (wave & 1) * 64;
    const int seg  = blockIdx.x >> 4;
    const int col0 = (blockIdx.x & 15) * 128;
    const int row0 = blockIdx.y * 128;
    const __bf16* __restrict__ Bp = segs.B[seg];

    f32x4 acc[4][4] = {};

    for (int k0 = 0; k0 < K; k0 += 32) {
#pragma unroll
        for (int i = 0; i < 2; i++) {
            int idx = tid + i * 256;             // 512 chunks of 8 bf16
            int r = idx >> 2, c = (idx & 3) * 8;
            gload16(&A [(size_t)(row0 + r) * K + k0 + c], &As[0][0] + idx * 8);
            gload16(&Bp[(size_t)(col0 + r) * K + k0 + c], &Bs[0][0] + idx * 8);
        }
        __syncthreads();
        bf16x8 af[4], bfr[4];
#pragma unroll
        for (int mt = 0; mt < 4; mt++)
            af[mt] = *reinterpret_cast<const bf16x8*>(&As[wm + mt * 16 + lr][lq * 8]);
#pragma unroll
        for (int nt = 0; nt < 4; nt++)
            bfr[nt] = *reinterpret_cast<const bf16x8*>(&Bs[wn + nt * 16 + lr][lq * 8]);
#pragma unroll
        for (int mt = 0; mt < 4; mt++)
#pragma unroll
            for (int nt = 0; nt < 4; nt++)
                acc[mt][nt] = __builtin_amdgcn_mfma_f32_16x16x32_bf16(af[mt], bfr[nt],
                                                                      acc[mt][nt], 0, 0, 0);
        __syncthreads();
    }
    const float* bias = segs.bias[seg];
    const float alpha = segs.alpha[seg];
    void* Cv = segs.C[seg];
#pragma unroll
    for (int mt = 0; mt < 4; mt++) {
#pragma unroll
        for (int nt = 0; nt < 4; nt++) {
            int col = col0 + wn + nt * 16 + lr;
            float bv = bias[col];
#pragma unroll
            for (int r = 0; r < 4; r++) {
                int row = row0 + wm + mt * 16 + lq * 4 + r;
                float v = alpha * (acc[mt][nt][r] + bv);
                if (OUT_BF16)
                    ((__bf16*)Cv)[(size_t)row * D + col] = (__bf16)v;
                else
                    ((float*)Cv)[(size_t)row * D + col] = v;
            }
        }
    }
}

// ---------------- mask @ V (per head), f32 out ------------------------------
// o2[q][h*HD+d] += sum_t mask[h][q][t] * V[t][h*HD+d]; z-split over t halves
__global__ __launch_bounds__(256) void maskv_kn(const float* __restrict__ mask,
                                                const __bf16* __restrict__ vT,
                                                float* __restrict__ o2a,
                                                float* __restrict__ o2b) {
    __shared__ __bf16 As[128][32];   // mask tile (bf16, converted in staging)
    __shared__ __bf16 Bs[128][32];   // vT tile
    const int tid = threadIdx.x;
    const int wave = tid >> 6, lane = tid & 63;
    const int lr = lane & 15, lq = lane >> 4;
    const int wm = (wave >> 1) * 64, wn = (wave & 1) * 64;
    const int h = blockIdx.y;
    const int row0 = blockIdx.x * 128;
    const int z = blockIdx.z;
    float* __restrict__ o2 = z ? o2b : o2a;

    f32x4 acc[4][4] = {};

    for (int t0 = z * (S / 2); t0 < (z + 1) * (S / 2); t0 += 32) {
        // A: mask f32 -> bf16 via VGPR (format conversion prevents DMA)
#pragma unroll
        for (int i = 0; i < 4; i++) {
            int idx = tid + i * 256;             // 1024 float4 chunks
            int r = idx >> 3, c = (idx & 7) * 4;
            float4 m4 = *reinterpret_cast<const float4*>(
                &mask[((size_t)h * S + row0 + r) * S + t0 + c]);
            bf16x4 b4 = { (__bf16)m4.x, (__bf16)m4.y, (__bf16)m4.z, (__bf16)m4.w };
            *reinterpret_cast<bf16x4*>(&As[r][c]) = b4;
        }
        // B: vT rows h*HD..+128, DMA
#pragma unroll
        for (int i = 0; i < 2; i++) {
            int idx = tid + i * 256;
            int r = idx >> 2, c = (idx & 3) * 8;
            gload16(&vT[(size_t)(h * HD + r) * S + t0 + c], &Bs[0][0] + idx * 8);
        }
        __syncthreads();
        bf16x8 af[4], bfr[4];
#pragma unroll
        for (int mt = 0; mt < 4; mt++)
            af[mt] = *reinterpret_cast<const bf16x8*>(&As[wm + mt * 16 + lr][lq * 8]);
#pragma unroll
        for (int nt = 0; nt < 4; nt++)
            bfr[nt] = *reinterpret_cast<const bf16x8*>(&Bs[wn + nt * 16 + lr][lq * 8]);
#pragma unroll
        for (int mt = 0; mt < 4; mt++)
#pragma unroll
            for (int nt = 0; nt < 4; nt++)
                acc[mt][nt] = __builtin_amdgcn_mfma_f32_16x16x32_bf16(af[mt], bfr[nt],
                                                                      acc[mt][nt], 0, 0, 0);
        __syncthreads();
    }
#pragma unroll
    for (int mt = 0; mt < 4; mt++)
#pragma unroll
        for (int nt = 0; nt < 4; nt++) {
            int col = wn + nt * 16 + lr;
#pragma unroll
            for (int r = 0; r < 4; r++) {
                int row = row0 + wm + mt * 16 + lq * 4 + r;
                o2[(size_t)row * D + h * HD + col] = acc[mt][nt][r];
            }
        }
}

// ---------------- fused attention: denom pass + (S*rd)@V + o2 + RMS*g -------
__global__ __launch_bounds__(256) void attn_kn(const __bf16* __restrict__ q,
                                               const __bf16* __restrict__ k,
                                               const __bf16* __restrict__ vT,
                                               const float* __restrict__ o2a,
                                               const float* __restrict__ o2b,
                                               const __bf16* __restrict__ g,
                                               const float* __restrict__ norm_w,
                                               __bf16* __restrict__ attn) {
    __shared__ __bf16 Ks[4][64][32];    // chunked for global_load_lds: Ks[kc][t][c]
    __shared__ __bf16 Vs[2][128][32];   // Vs[kc2][d][c]
    __shared__ __bf16 Ps[4][16][72];    // per-wave P tile (16 q-rows x 64 t)
    const int h = blockIdx.y, qt = blockIdx.x;
    const int tid = threadIdx.x, wave = tid >> 6, lane = tid & 63;
    const int lr = lane & 15, lq = lane >> 4;
    const int qr0 = qt * 64 + wave * 16;

    bf16x8 qf[4];
#pragma unroll
    for (int kc = 0; kc < 4; kc++)
        qf[kc] = *reinterpret_cast<const bf16x8*>(
            &q[(size_t)(qr0 + lr) * D + h * HD + kc * 32 + lq * 8]);

    // ---- pass 1: row abs-sums of QK^T -> rd ----
    float absacc[4] = {0.f, 0.f, 0.f, 0.f};
    for (int t0 = 0; t0 < S; t0 += 64) {
#pragma unroll
        for (int i = 0; i < 4; i++) {
            int idx = tid + i * 256;             // kc = i, r = (idx>>2)&63, c8 = idx&3
            int r = (idx >> 2) & 63, c = (idx & 3) * 8;
            gload16(&k[(size_t)(t0 + r) * D + h * HD + i * 32 + c], &Ks[0][0][0] + idx * 8);
        }
        __syncthreads();
#pragma unroll
        for (int ts = 0; ts < 4; ts++) {
            f32x4 c = {0.f, 0.f, 0.f, 0.f};
#pragma unroll
            for (int kc = 0; kc < 4; kc++) {
                bf16x8 kf = *reinterpret_cast<const bf16x8*>(&Ks[kc][ts * 16 + lr][lq * 8]);
                c = __builtin_amdgcn_mfma_f32_16x16x32_bf16(qf[kc], kf, c, 0, 0, 0);
            }
#pragma unroll
            for (int r2 = 0; r2 < 4; r2++) absacc[r2] += fabsf(c[r2]);
        }
        __syncthreads();
    }
    float rd[4];
#pragma unroll
    for (int r2 = 0; r2 < 4; r2++) {
        float v = absacc[r2];
#pragma unroll
        for (int off = 1; off < 16; off <<= 1) v += __shfl_xor(v, off, 64);
        rd[r2] = 1.0f / fminf(fmaxf(v, 1.0f), 50000.0f);
    }

    // ---- pass 2: O1 = (QK^T * rd) @ V ----
    f32x4 o[8] = {};
    for (int t0 = 0; t0 < S; t0 += 64) {
#pragma unroll
        for (int i = 0; i < 4; i++) {
            int idx = tid + i * 256;
            int rk = (idx >> 2) & 63, ck = (idx & 3) * 8;
            gload16(&k[(size_t)(t0 + rk) * D + h * HD + i * 32 + ck], &Ks[0][0][0] + idx * 8);
            int kc2 = idx >> 9, rv = (idx >> 2) & 127, cv = (idx & 3) * 8;
            gload16(&vT[(size_t)(h * HD + rv) * S + t0 + kc2 * 32 + cv], &Vs[0][0][0] + idx * 8);
        }
        __syncthreads();
#pragma unroll
        for (int ts = 0; ts < 4; ts++) {
            f32x4 c = {0.f, 0.f, 0.f, 0.f};
#pragma unroll
            for (int kc = 0; kc < 4; kc++) {
                bf16x8 kf = *reinterpret_cast<const bf16x8*>(&Ks[kc][ts * 16 + lr][lq * 8]);
                c = __builtin_amdgcn_mfma_f32_16x16x32_bf16(qf[kc], kf, c, 0, 0, 0);
            }
#pragma unroll
            for (int r2 = 0; r2 < 4; r2++)
                Ps[wave][lq * 4 + r2][ts * 16 + lr] = (__bf16)(c[r2] * rd[r2]);
        }
#pragma unroll
        for (int kc2 = 0; kc2 < 2; kc2++) {
            bf16x8 pf = *reinterpret_cast<const bf16x8*>(&Ps[wave][lr][kc2 * 32 + lq * 8]);
#pragma unroll
            for (int nt = 0; nt < 8; nt++) {
                bf16x8 vf = *reinterpret_cast<const bf16x8*>(&Vs[kc2][nt * 16 + lr][lq * 8]);
                o[nt] = __builtin_amdgcn_mfma_f32_16x16x32_bf16(pf, vf, o[nt], 0, 0, 0);
            }
        }
        __syncthreads();
    }

    // ---- epilogue: O = O1 + maskV, RMS over hd, * norm_w * g ----
    float otot[8][4];
    float ssum[4] = {0.f, 0.f, 0.f, 0.f};
#pragma unroll
    for (int nt = 0; nt < 8; nt++) {
        int col = nt * 16 + lr;
#pragma unroll
        for (int r2 = 0; r2 < 4; r2++) {
            size_t a = (size_t)(qr0 + lq * 4 + r2) * D + h * HD + col;
            float v = o[nt][r2] + o2a[a] + o2b[a];
            otot[nt][r2] = v;
            ssum[r2] += v * v;
        }
    }
#pragma unroll
    for (int r2 = 0; r2 < 4; r2++) {
#pragma unroll
        for (int off = 1; off < 16; off <<= 1) ssum[r2] += __shfl_xor(ssum[r2], off, 64);
    }
    float rinv[4];
#pragma unroll
    for (int r2 = 0; r2 < 4; r2++) rinv[r2] = rsqrtf(ssum[r2] * (1.0f / HD) + 1e-5f);
#pragma unroll
    for (int nt = 0; nt < 8; nt++) {
        int col = nt * 16 + lr;
        float nw = norm_w[col];
#pragma unroll
        for (int r2 = 0; r2 < 4; r2++) {
            int row = qr0 + lq * 4 + r2;
            float val = otot[nt][r2] * rinv[r2] * nw * (float)g[(size_t)row * D + h * HD + col];
            attn[(size_t)row * D + h * HD + col] = (__bf16)val;
        }
    }
}

extern "C" void kernel_launch(void* const* d_in, const int* in_sizes, int n_in,
                              void* d_out, int out_size, void* d_ws, size_t ws_size,
                              hipStream_t stream) {
    const float* x    = (const float*)d_in[0];
    const float* fcos = (const float*)d_in[1];
    const float* fsin = (const float*)d_in[2];
    const float* mask = (const float*)d_in[3];
    const float* Wq   = (const float*)d_in[4];
    const float* bq   = (const float*)d_in[5];
    const float* Wk   = (const float*)d_in[6];
    const float* bk   = (const float*)d_in[7];
    const float* Wv   = (const float*)d_in[8];
    const float* bv   = (const float*)d_in[9];
    const float* Wg   = (const float*)d_in[10];
    const float* bg   = (const float*)d_in[11];
    const float* Wp   = (const float*)d_in[12];
    const float* bp   = (const float*)d_in[13];
    const float* normw= (const float*)d_in[14];

    char* w = (char*)d_ws;
    auto alloc = [&](size_t b) { void* p = (void*)w; w += (b + 255) & ~(size_t)255; return p; };
    const size_t SD = (size_t)S * D;

    __bf16* xb  = (__bf16*)alloc(SD * 2);
    __bf16* wqb = (__bf16*)alloc(SD * 2);
    __bf16* wkb = (__bf16*)alloc(SD * 2);
    __bf16* wvb = (__bf16*)alloc(SD * 2);
    __bf16* wgb = (__bf16*)alloc(SD * 2);
    __bf16* wpb = (__bf16*)alloc(SD * 2);
    __bf16* qb  = (__bf16*)alloc(SD * 2);
    __bf16* kb  = (__bf16*)alloc(SD * 2);
    __bf16* vb  = (__bf16*)alloc(SD * 2);
    __bf16* gb  = (__bf16*)alloc(SD * 2);
    __bf16* vTb = (__bf16*)alloc(SD * 2);
    // aliases (time-disjoint): o2a over {wqb,wkb}, o2b over {wvb,wgb}, atb over xb
    float*  o2a = (float*)wqb;   // S*D f32 = 2 bf16 slabs
    float*  o2b = (float*)wvb;
    __bf16* atb = xb;

    const int n4 = (int)(SD / 4);
    const int cb = n4 / 256;
    f32_to_bf16_kn<<<cb, 256, 0, stream>>>(x,  xb,  n4);
    f32_to_bf16_kn<<<cb, 256, 0, stream>>>(Wq, wqb, n4);
    f32_to_bf16_kn<<<cb, 256, 0, stream>>>(Wk, wkb, n4);
    f32_to_bf16_kn<<<cb, 256, 0, stream>>>(Wv, wvb, n4);
    f32_to_bf16_kn<<<cb, 256, 0, stream>>>(Wg, wgb, n4);
    f32_to_bf16_kn<<<cb, 256, 0, stream>>>(Wp, wpb, n4);

    const float scaling = 0.08838834764831845f;  // 128^-0.5
    SegArgs qkvg;
    qkvg.B[0] = wqb; qkvg.B[1] = wkb; qkvg.B[2] = wvb; qkvg.B[3] = wgb;
    qkvg.bias[0] = bq; qkvg.bias[1] = bk; qkvg.bias[2] = bv; qkvg.bias[3] = bg;
    qkvg.C[0] = qb; qkvg.C[1] = kb; qkvg.C[2] = vb; qkvg.C[3] = gb;
    qkvg.alpha[0] = 1.0f; qkvg.alpha[1] = scaling; qkvg.alpha[2] = 1.0f; qkvg.alpha[3] = 1.0f;
    gemm4_kn<1><<<dim3(64, 16), 256, 0, stream>>>(xb, qkvg, D);

    rope_kn<<<(S * D / 2) / 256, 256, 0, stream>>>(qb, fcos, fsin);
    rope_kn<<<(S * D / 2) / 256, 256, 0, stream>>>(kb, fcos, fsin);

    transpose_kn<<<dim3(64, 64), dim3(32, 8), 0, stream>>>(vb, vTb);

    maskv_kn<<<dim3(16, 16, 2), 256, 0, stream>>>(mask, vTb, o2a, o2b);

    attn_kn<<<dim3(32, 16), 256, 0, stream>>>(qb, kb, vTb, o2a, o2b, gb, normw, atb);

    SegArgs pseg;
    pseg.B[0] = pseg.B[1] = pseg.B[2] = pseg.B[3] = wpb;
    pseg.bias[0] = pseg.bias[1] = pseg.bias[2] = pseg.bias[3] = bp;
    pseg.C[0] = pseg.C[1] = pseg.C[2] = pseg.C[3] = d_out;
    pseg.alpha[0] = pseg.alpha[1] = pseg.alpha[2] = pseg.alpha[3] = 1.0f;
    gemm4_kn<0><<<dim3(16, 16), 256, 0, stream>>>(atb, pseg, D);
}

// Round 4
// 705.583 us; speedup vs baseline: 1.4040x; 1.0736x over previous
//
#include <hip/hip_runtime.h>
#include <hip/hip_bf16.h>
#include <stdint.h>

#define S 2048
#define D 2048
#define H 16
#define HD 128

typedef __bf16 bf16x8 __attribute__((ext_vector_type(8)));
typedef __bf16 bf16x4 __attribute__((ext_vector_type(4)));
typedef float f32x4 __attribute__((ext_vector_type(4)));

// async global->LDS DMA, 16B per lane; LDS dest = wave-uniform base + lane*16
__device__ __forceinline__ void gload16(const void* g, void* l) {
    __builtin_amdgcn_global_load_lds(
        (const __attribute__((address_space(1))) unsigned int*)g,
        (__attribute__((address_space(3))) unsigned int*)l, 16, 0, 0);
}

// ---------------- merged f32 -> bf16 convert (6 arrays, exact grid) ---------
struct CvtArgs { const float* src[6]; __bf16* dst[6]; };

__global__ void cvt_kn(CvtArgs a) {
    int which = blockIdx.x >> 12;                    // 4096 blocks per array
    int i = (blockIdx.x & 4095) * 256 + threadIdx.x; // < SD/4
    float4 v = reinterpret_cast<const float4*>(a.src[which])[i];
    bf16x4 o = { (__bf16)v.x, (__bf16)v.y, (__bf16)v.z, (__bf16)v.w };
    reinterpret_cast<bf16x4*>(a.dst[which])[i] = o;
}

// ---------------- fused multi-output GEMM -----------------------------------
// seg = blockIdx.x>>4 selects weight/bias/output/op.
// op: 0 = plain bf16, 1 = rope bf16 (q/k), 2 = direct-transpose bf16 (vT),
//     3 = plain f32
struct SegArgs {
    const __bf16* B[4];
    const float*  bias[4];
    void*         C[4];
    float         alpha[4];
    int           op[4];
};

__global__ __launch_bounds__(256) void gemm4_kn(const __bf16* __restrict__ A,
                                                SegArgs segs,
                                                const float* __restrict__ fcos,
                                                const float* __restrict__ fsin,
                                                int K) {
    __shared__ __bf16 As[128][32];   // unpadded: required by global_load_lds
    __shared__ __bf16 Bs[128][32];
    const int tid = threadIdx.x;
    const int wave = tid >> 6, lane = tid & 63;
    const int lr = lane & 15, lq = lane >> 4;
    const int wm = (wave >> 1) * 64, wn = (wave & 1) * 64;
    const int seg  = blockIdx.x >> 4;
    const int col0 = (blockIdx.x & 15) * 128;
    const int row0 = blockIdx.y * 128;
    const __bf16* __restrict__ Bp = segs.B[seg];

    f32x4 acc[4][4] = {};

    for (int k0 = 0; k0 < K; k0 += 32) {
#pragma unroll
        for (int i = 0; i < 2; i++) {
            int idx = tid + i * 256;             // 512 chunks of 8 bf16
            int r = idx >> 2, c = (idx & 3) * 8;
            gload16(&A [(size_t)(row0 + r) * K + k0 + c], &As[0][0] + idx * 8);
            gload16(&Bp[(size_t)(col0 + r) * K + k0 + c], &Bs[0][0] + idx * 8);
        }
        __syncthreads();
        bf16x8 af[4], bfr[4];
#pragma unroll
        for (int mt = 0; mt < 4; mt++)
            af[mt] = *reinterpret_cast<const bf16x8*>(&As[wm + mt * 16 + lr][lq * 8]);
#pragma unroll
        for (int nt = 0; nt < 4; nt++)
            bfr[nt] = *reinterpret_cast<const bf16x8*>(&Bs[wn + nt * 16 + lr][lq * 8]);
#pragma unroll
        for (int mt = 0; mt < 4; mt++)
#pragma unroll
            for (int nt = 0; nt < 4; nt++)
                acc[mt][nt] = __builtin_amdgcn_mfma_f32_16x16x32_bf16(af[mt], bfr[nt],
                                                                      acc[mt][nt], 0, 0, 0);
        __syncthreads();
    }
    const float* bias = segs.bias[seg];
    const float alpha = segs.alpha[seg];
    const int op = segs.op[seg];
    void* Cv = segs.C[seg];

    if (op == 2) {
        // direct transpose: vT[d][s], 4 consecutive rows per lane (8B store)
#pragma unroll
        for (int mt = 0; mt < 4; mt++)
#pragma unroll
            for (int nt = 0; nt < 4; nt++) {
                int col = col0 + wn + nt * 16 + lr;
                float bv = bias[col];
                int rowb = row0 + wm + mt * 16 + lq * 4;
                bf16x4 o4;
#pragma unroll
                for (int r = 0; r < 4; r++) o4[r] = (__bf16)(acc[mt][nt][r] + bv);
                *reinterpret_cast<bf16x4*>(&((__bf16*)Cv)[(size_t)col * S + rowb]) = o4;
            }
    } else if (op == 1) {
        // rope epilogue: pair partner value lives in lane lr^1
#pragma unroll
        for (int mt = 0; mt < 4; mt++)
#pragma unroll
            for (int nt = 0; nt < 4; nt++) {
                int col = col0 + wn + nt * 16 + lr;
                float bv = bias[col];
                int i = (col & 127) >> 1;
                int odd = lr & 1;
#pragma unroll
                for (int r = 0; r < 4; r++) {
                    int row = row0 + wm + mt * 16 + lq * 4 + r;
                    float v = alpha * (acc[mt][nt][r] + bv);
                    float p = __shfl_xor(v, 1, 64);
                    float c = fcos[row * 64 + i];
                    float sn = fsin[row * 64 + i];
                    float out = odd ? (p * sn + v * c) : (v * c - p * sn);
                    ((__bf16*)Cv)[(size_t)row * D + col] = (__bf16)out;
                }
            }
    } else {
#pragma unroll
        for (int mt = 0; mt < 4; mt++)
#pragma unroll
            for (int nt = 0; nt < 4; nt++) {
                int col = col0 + wn + nt * 16 + lr;
                float bv = bias[col];
#pragma unroll
                for (int r = 0; r < 4; r++) {
                    int row = row0 + wm + mt * 16 + lq * 4 + r;
                    float v = alpha * (acc[mt][nt][r] + bv);
                    if (op == 3)
                        ((float*)Cv)[(size_t)row * D + col] = v;
                    else
                        ((__bf16*)Cv)[(size_t)row * D + col] = (__bf16)v;
                }
            }
    }
}

// ---------------- fused attention -------------------------------------------
// One pass over t: U2 += mask@V ; S = QK^T ; absacc += |S| ; U += S@V.
// Epilogue: O = rd*U + U2 ; RMS(hd) ; *norm_w ; *g  -> bf16.
__global__ __launch_bounds__(256) void attn_kn(const __bf16* __restrict__ q,
                                               const __bf16* __restrict__ k,
                                               const __bf16* __restrict__ vT,
                                               const float* __restrict__ mask,
                                               const __bf16* __restrict__ g,
                                               const float* __restrict__ norm_w,
                                               __bf16* __restrict__ attn) {
    __shared__ __bf16 Ks[4][64][32];    // chunked for global_load_lds
    __shared__ __bf16 Vs[2][128][32];
    __shared__ __bf16 Ps[4][16][72];    // per-wave P tile (16 q-rows x 64 t)
    const int h = blockIdx.y, qt = blockIdx.x;
    const int tid = threadIdx.x, wave = tid >> 6, lane = tid & 63;
    const int lr = lane & 15, lq = lane >> 4;
    const int qr0 = qt * 64 + wave * 16;

    bf16x8 qf[4];
#pragma unroll
    for (int kc = 0; kc < 4; kc++)
        qf[kc] = *reinterpret_cast<const bf16x8*>(
            &q[(size_t)(qr0 + lr) * D + h * HD + kc * 32 + lq * 8]);

    float absacc[4] = {0.f, 0.f, 0.f, 0.f};
    f32x4 U[8] = {};
    f32x4 U2[8] = {};

    for (int t0 = 0; t0 < S; t0 += 64) {
        // K tile: 1024 x 16B chunks -> Ks[4][64][32]
#pragma unroll
        for (int i = 0; i < 4; i++) {
            int idx = tid + i * 256;
            int rk = (idx >> 2) & 63, ck = (idx & 3) * 8;
            gload16(&k[(size_t)(t0 + rk) * D + h * HD + i * 32 + ck], &Ks[0][0][0] + idx * 8);
        }
        // V tile: 1024 x 16B chunks -> Vs[2][128][32]  (FIX: was i<2, half-tile)
#pragma unroll
        for (int i = 0; i < 4; i++) {
            int idx = tid + i * 256;
            int kc2 = idx >> 9, rv = (idx >> 2) & 127, cv = (idx & 3) * 8;
            gload16(&vT[(size_t)(h * HD + rv) * S + t0 + kc2 * 32 + cv], &Vs[0][0][0] + idx * 8);
        }
        // mask tile -> per-wave Ps (f32->bf16 in VGPR; plain loads overlap DMA)
        bf16x4 mrow[4];
#pragma unroll
        for (int it = 0; it < 4; it++) {
            int idx = it * 64 + lane;
            int r = idx >> 4, c4 = (idx & 15) * 4;
            float4 m4 = *reinterpret_cast<const float4*>(
                &mask[((size_t)h * S + qr0 + r) * S + t0 + c4]);
            mrow[it] = bf16x4{ (__bf16)m4.x, (__bf16)m4.y, (__bf16)m4.z, (__bf16)m4.w };
        }
        __syncthreads();
#pragma unroll
        for (int it = 0; it < 4; it++) {
            int idx = it * 64 + lane;
            int r = idx >> 4, c4 = (idx & 15) * 4;
            *reinterpret_cast<bf16x4*>(&Ps[wave][r][c4]) = mrow[it];
        }
        // U2 += mask @ V  (per-wave Ps, same-wave LDS ordering)
#pragma unroll
        for (int kc2 = 0; kc2 < 2; kc2++) {
            bf16x8 pf = *reinterpret_cast<const bf16x8*>(&Ps[wave][lr][kc2 * 32 + lq * 8]);
#pragma unroll
            for (int nt = 0; nt < 8; nt++) {
                bf16x8 vf = *reinterpret_cast<const bf16x8*>(&Vs[kc2][nt * 16 + lr][lq * 8]);
                U2[nt] = __builtin_amdgcn_mfma_f32_16x16x32_bf16(pf, vf, U2[nt], 0, 0, 0);
            }
        }
        // S tile, abs-sum, P (unscaled) -> Ps
#pragma unroll
        for (int ts = 0; ts < 4; ts++) {
            f32x4 c = {0.f, 0.f, 0.f, 0.f};
#pragma unroll
            for (int kc = 0; kc < 4; kc++) {
                bf16x8 kf = *reinterpret_cast<const bf16x8*>(&Ks[kc][ts * 16 + lr][lq * 8]);
                c = __builtin_amdgcn_mfma_f32_16x16x32_bf16(qf[kc], kf, c, 0, 0, 0);
            }
#pragma unroll
            for (int r2 = 0; r2 < 4; r2++) {
                absacc[r2] += fabsf(c[r2]);
                Ps[wave][lq * 4 + r2][ts * 16 + lr] = (__bf16)c[r2];
            }
        }
        // U += S @ V
#pragma unroll
        for (int kc2 = 0; kc2 < 2; kc2++) {
            bf16x8 pf = *reinterpret_cast<const bf16x8*>(&Ps[wave][lr][kc2 * 32 + lq * 8]);
#pragma unroll
            for (int nt = 0; nt < 8; nt++) {
                bf16x8 vf = *reinterpret_cast<const bf16x8*>(&Vs[kc2][nt * 16 + lr][lq * 8]);
                U[nt] = __builtin_amdgcn_mfma_f32_16x16x32_bf16(pf, vf, U[nt], 0, 0, 0);
            }
        }
        __syncthreads();
    }

    // rd = 1/clip(sum_t |S|)
    float rd[4];
#pragma unroll
    for (int r2 = 0; r2 < 4; r2++) {
        float v = absacc[r2];
#pragma unroll
        for (int off = 1; off < 16; off <<= 1) v += __shfl_xor(v, off, 64);
        rd[r2] = 1.0f / fminf(fmaxf(v, 1.0f), 50000.0f);
    }

    // O = rd*U + U2, RMS over hd, * norm_w * g
    float otot[8][4];
    float ssum[4] = {0.f, 0.f, 0.f, 0.f};
#pragma unroll
    for (int nt = 0; nt < 8; nt++)
#pragma unroll
        for (int r2 = 0; r2 < 4; r2++) {
            float v = U[nt][r2] * rd[r2] + U2[nt][r2];
            otot[nt][r2] = v;
            ssum[r2] += v * v;
        }
#pragma unroll
    for (int r2 = 0; r2 < 4; r2++) {
#pragma unroll
        for (int off = 1; off < 16; off <<= 1) ssum[r2] += __shfl_xor(ssum[r2], off, 64);
    }
    float rinv[4];
#pragma unroll
    for (int r2 = 0; r2 < 4; r2++) rinv[r2] = rsqrtf(ssum[r2] * (1.0f / HD) + 1e-5f);
#pragma unroll
    for (int nt = 0; nt < 8; nt++) {
        int col = nt * 16 + lr;
        float nw = norm_w[col];
#pragma unroll
        for (int r2 = 0; r2 < 4; r2++) {
            int row = qr0 + lq * 4 + r2;
            float val = otot[nt][r2] * rinv[r2] * nw * (float)g[(size_t)row * D + h * HD + col];
            attn[(size_t)row * D + h * HD + col] = (__bf16)val;
        }
    }
}

extern "C" void kernel_launch(void* const* d_in, const int* in_sizes, int n_in,
                              void* d_out, int out_size, void* d_ws, size_t ws_size,
                              hipStream_t stream) {
    const float* x    = (const float*)d_in[0];
    const float* fcos = (const float*)d_in[1];
    const float* fsin = (const float*)d_in[2];
    const float* mask = (const float*)d_in[3];
    const float* Wq   = (const float*)d_in[4];
    const float* bq   = (const float*)d_in[5];
    const float* Wk   = (const float*)d_in[6];
    const float* bk   = (const float*)d_in[7];
    const float* Wv   = (const float*)d_in[8];
    const float* bv   = (const float*)d_in[9];
    const float* Wg   = (const float*)d_in[10];
    const float* bg   = (const float*)d_in[11];
    const float* Wp   = (const float*)d_in[12];
    const float* bp   = (const float*)d_in[13];
    const float* normw= (const float*)d_in[14];

    char* w = (char*)d_ws;
    auto alloc = [&](size_t b) { void* p = (void*)w; w += (b + 255) & ~(size_t)255; return p; };
    const size_t SD = (size_t)S * D;

    __bf16* xb  = (__bf16*)alloc(SD * 2);
    __bf16* wqb = (__bf16*)alloc(SD * 2);
    __bf16* wkb = (__bf16*)alloc(SD * 2);
    __bf16* wvb = (__bf16*)alloc(SD * 2);
    __bf16* wgb = (__bf16*)alloc(SD * 2);
    __bf16* wpb = (__bf16*)alloc(SD * 2);
    __bf16* qb  = (__bf16*)alloc(SD * 2);
    __bf16* kb  = (__bf16*)alloc(SD * 2);
    __bf16* vTb = (__bf16*)alloc(SD * 2);
    __bf16* gb  = (__bf16*)alloc(SD * 2);
    __bf16* atb = xb;   // alias: xb dead after QKVG gemm

    CvtArgs ca;
    ca.src[0] = x;  ca.dst[0] = xb;
    ca.src[1] = Wq; ca.dst[1] = wqb;
    ca.src[2] = Wk; ca.dst[2] = wkb;
    ca.src[3] = Wv; ca.dst[3] = wvb;
    ca.src[4] = Wg; ca.dst[4] = wgb;
    ca.src[5] = Wp; ca.dst[5] = wpb;
    cvt_kn<<<6 * 4096, 256, 0, stream>>>(ca);

    const float scaling = 0.08838834764831845f;  // 128^-0.5
    SegArgs qkvg;
    qkvg.B[0] = wqb; qkvg.B[1] = wkb; qkvg.B[2] = wvb; qkvg.B[3] = wgb;
    qkvg.bias[0] = bq; qkvg.bias[1] = bk; qkvg.bias[2] = bv; qkvg.bias[3] = bg;
    qkvg.C[0] = qb; qkvg.C[1] = kb; qkvg.C[2] = vTb; qkvg.C[3] = gb;
    qkvg.alpha[0] = 1.0f; qkvg.alpha[1] = scaling; qkvg.alpha[2] = 1.0f; qkvg.alpha[3] = 1.0f;
    qkvg.op[0] = 1; qkvg.op[1] = 1; qkvg.op[2] = 2; qkvg.op[3] = 0;
    gemm4_kn<<<dim3(64, 16), 256, 0, stream>>>(xb, qkvg, fcos, fsin, D);

    attn_kn<<<dim3(32, 16), 256, 0, stream>>>(qb, kb, vTb, mask, gb, normw, atb);

    SegArgs pseg;
    pseg.B[0] = pseg.B[1] = pseg.B[2] = pseg.B[3] = wpb;
    pseg.bias[0] = pseg.bias[1] = pseg.bias[2] = pseg.bias[3] = bp;
    pseg.C[0] = pseg.C[1] = pseg.C[2] = pseg.C[3] = d_out;
    pseg.alpha[0] = pseg.alpha[1] = pseg.alpha[2] = pseg.alpha[3] = 1.0f;
    pseg.op[0] = pseg.op[1] = pseg.op[2] = pseg.op[3] = 3;
    gemm4_kn<<<dim3(16, 16), 256, 0, stream>>>(atb, pseg, fcos, fsin, D);
}